// Round 1
// baseline (23356.602 us; speedup 1.0000x reference)
//
#include <hip/hip_runtime.h>
#include <hip/hip_bf16.h>

#define SB 64      // batch
#define SS 512     // seq len
#define SI 256     // input dim
#define SH 1024    // hidden dim
#define SO 256     // output dim
#define NL 3       // layers

typedef __attribute__((ext_vector_type(8))) short bf16x8;
typedef __attribute__((ext_vector_type(4))) float f32x4;

__device__ __forceinline__ unsigned short f2bf(float f) {
  unsigned int u = __float_as_uint(f);
  u += 0x7fff + ((u >> 16) & 1);   // RNE
  return (unsigned short)(u >> 16);
}

// ---------------- prologue kernels ----------------

// src: (K, N) fp32 row-major  ->  dst: (N, K) bf16 row-major
__global__ void k_transpose(const float* __restrict__ src, unsigned short* __restrict__ dst,
                            int K, int N) {
  __shared__ float tile[32][33];
  int n0 = blockIdx.x * 32, k0 = blockIdx.y * 32;
  int tx = threadIdx.x & 31, ty = threadIdx.x >> 5;  // 32 x 8
  for (int i = ty; i < 32; i += 8)
    tile[i][tx] = src[(size_t)(k0 + i) * N + (n0 + tx)];
  __syncthreads();
  for (int i = ty; i < 32; i += 8)
    dst[(size_t)(n0 + i) * K + (k0 + tx)] = f2bf(tile[tx][i]);
}

// h0: (B, L, H) -> h_f32/h_bf: (L, B, H)
__global__ void k_init_h(const float* __restrict__ h0, float* __restrict__ h_f32,
                         unsigned short* __restrict__ h_bf) {
  int idx = blockIdx.x * blockDim.x + threadIdx.x;
  if (idx >= NL * SB * SH) return;
  int l = idx >> 16; int rem = idx & 65535; int b = rem >> 10; int c = rem & 1023;
  float v = h0[((size_t)b * NL + l) * SH + c];
  h_f32[idx] = v;
  h_bf[idx] = f2bf(v);
}

__global__ void k_final(const float* __restrict__ h_f32, float* __restrict__ out) {
  int idx = blockIdx.x * blockDim.x + threadIdx.x;
  if (idx >= NL * SB * SH) return;
  int l = idx >> 16; int rem = idx & 65535; int b = rem >> 10; int c = rem & 1023;
  out[(size_t)SB * SS * SO + ((size_t)b * NL + l) * SH + c] = h_f32[idx];
}

// ---------------- GEMM helper ----------------
// Wave computes a 16(M) x 16(N) tile; A: (M,K) row-major bf16, B: (N,K) row-major bf16 (B^T).
template<int K>
__device__ __forceinline__ void gemm_k(const unsigned short* __restrict__ Ap,
                                       const unsigned short* __restrict__ Bp,
                                       f32x4& acc0, f32x4& acc1) {
#pragma unroll 8
  for (int k0 = 0; k0 < K; k0 += 64) {
    bf16x8 a0 = *(const bf16x8*)(Ap + k0);
    bf16x8 b0 = *(const bf16x8*)(Bp + k0);
    bf16x8 a1 = *(const bf16x8*)(Ap + k0 + 32);
    bf16x8 b1 = *(const bf16x8*)(Bp + k0 + 32);
    acc0 = __builtin_amdgcn_mfma_f32_16x16x32_bf16(a0, b0, acc0, 0, 0, 0);
    acc1 = __builtin_amdgcn_mfma_f32_16x16x32_bf16(a1, b1, acc1, 0, 0, 0);
  }
}

// ---------------- stage A: zr GEMMs + gx_g, plus y(t-3) ----------------
// blocks 0..575: 3 layers x 192 col-tiles (16 cols). blocks 576..591: y tiles.
__global__ __launch_bounds__(256) void k_stageA(
    int s,
    const float* __restrict__ x,
    const unsigned short* __restrict__ Wx0t,
    const unsigned short* __restrict__ Wx1t,
    const unsigned short* __restrict__ Wx2t,
    const unsigned short* __restrict__ Wh0t,
    const unsigned short* __restrict__ Wh1t,
    const unsigned short* __restrict__ Wh2t,
    const unsigned short* __restrict__ Wyt,
    const float* __restrict__ bh0,
    const float* __restrict__ bhx,   // (2, 3H)
    const float* __restrict__ by,
    const unsigned short* __restrict__ h_bf,   // (3,B,H)
    const float* __restrict__ h_f32,           // (3,B,H)
    float* __restrict__ z_f32,                 // (3,B,H)
    unsigned short* __restrict__ rh_bf,        // (3,B,H)
    float* __restrict__ gxg_f32,               // (3,B,H)
    float* __restrict__ out) {
  const int tid  = threadIdx.x;
  const int wid  = tid >> 6;
  const int lane = tid & 63;
  const int lrow = lane & 15;
  const int kg   = lane >> 4;
  const int row0 = wid << 4;
  const int blk  = blockIdx.x;

  f32x4 acc0 = {0.f, 0.f, 0.f, 0.f};
  f32x4 acc1 = {0.f, 0.f, 0.f, 0.f};

  if (blk < 576) {
    const int l  = blk / 192;
    const int c0 = (blk % 192) << 4;
    const int t  = s - l;
    if (t < 0 || t >= SS) return;
    const int col = c0 + lrow;

    const unsigned short* Wht = (l == 0) ? Wh0t : ((l == 1) ? Wh1t : Wh2t);
    const float* bias = (l == 0) ? bh0 : (bhx + (size_t)(l - 1) * 3 * SH);

    if (l == 0) {
      // x-side GEMM, K = SI, convert fp32 -> bf16 in-register
      const float* Ax = x + ((size_t)(row0 + lrow) * SS + t) * SI + kg * 8;
      const unsigned short* Bp = Wx0t + (size_t)col * SI + kg * 8;
#pragma unroll
      for (int k0 = 0; k0 < SI; k0 += 64) {
        bf16x8 a0, a1;
        const float* A0 = Ax + k0;
        const float* A1 = Ax + k0 + 32;
#pragma unroll
        for (int q = 0; q < 8; ++q) {
          a0[q] = (short)f2bf(A0[q]);
          a1[q] = (short)f2bf(A1[q]);
        }
        bf16x8 b0 = *(const bf16x8*)(Bp + k0);
        bf16x8 b1 = *(const bf16x8*)(Bp + k0 + 32);
        acc0 = __builtin_amdgcn_mfma_f32_16x16x32_bf16(a0, b0, acc0, 0, 0, 0);
        acc1 = __builtin_amdgcn_mfma_f32_16x16x32_bf16(a1, b1, acc1, 0, 0, 0);
      }
    } else {
      const unsigned short* curh = h_bf + (size_t)(l - 1) * SB * SH;
      const unsigned short* Wxt  = (l == 1) ? Wx1t : Wx2t;
      gemm_k<SH>(curh + (size_t)(row0 + lrow) * SH + kg * 8,
                 Wxt + (size_t)col * SH + kg * 8, acc0, acc1);
    }

    if (c0 < 2 * SH) {
      // h-side zr GEMM
      const unsigned short* hb = h_bf + (size_t)l * SB * SH;
      gemm_k<SH>(hb + (size_t)(row0 + lrow) * SH + kg * 8,
                 Wht + (size_t)col * SH + kg * 8, acc0, acc1);
      const float bsum = bias[col];
      const float* hf = h_f32 + (size_t)l * SB * SH;
#pragma unroll
      for (int j = 0; j < 4; ++j) {
        const int row = row0 + kg * 4 + j;
        const float v = acc0[j] + acc1[j] + bsum;
        const float sg = 1.f / (1.f + __expf(-v));
        if (col < SH) {
          z_f32[((size_t)l * SB + row) * SH + col] = sg;
        } else {
          const int cg = col - SH;
          const float hp = hf[(size_t)row * SH + cg];
          rh_bf[((size_t)l * SB + row) * SH + cg] = f2bf(sg * hp);
        }
      }
    } else {
      const int cg = col - 2 * SH;
#pragma unroll
      for (int j = 0; j < 4; ++j) {
        const int row = row0 + kg * 4 + j;
        gxg_f32[((size_t)l * SB + row) * SH + cg] = acc0[j] + acc1[j];
      }
    }
  } else {
    // y projection for t = s - 3 using h_bf[2] (still holds h2(t))
    const int ty = s - 3;
    if (ty < 0 || ty >= SS) return;
    const int c0  = (blk - 576) << 4;
    const int col = c0 + lrow;
    const unsigned short* h2 = h_bf + (size_t)2 * SB * SH;
    gemm_k<SH>(h2 + (size_t)(row0 + lrow) * SH + kg * 8,
               Wyt + (size_t)col * SH + kg * 8, acc0, acc1);
    const float bsum = by[col];
#pragma unroll
    for (int j = 0; j < 4; ++j) {
      const int row = row0 + kg * 4 + j;
      out[((size_t)row * SS + ty) * SO + col] = acc0[j] + acc1[j] + bsum;
    }
  }
}

// ---------------- stage B: g GEMM + state update ----------------
// 192 blocks: 3 layers x 64 col-tiles (16 cols of H)
__global__ __launch_bounds__(256) void k_stageB(
    int s,
    const unsigned short* __restrict__ Wh0t,
    const unsigned short* __restrict__ Wh1t,
    const unsigned short* __restrict__ Wh2t,
    const float* __restrict__ bh0,
    const float* __restrict__ bhx,
    const unsigned short* __restrict__ rh_bf,
    const float* __restrict__ z_f32,
    const float* __restrict__ gxg_f32,
    float* __restrict__ h_f32,
    unsigned short* __restrict__ h_bf) {
  const int tid  = threadIdx.x;
  const int wid  = tid >> 6;
  const int lane = tid & 63;
  const int lrow = lane & 15;
  const int kg   = lane >> 4;
  const int row0 = wid << 4;
  const int blk  = blockIdx.x;
  const int l    = blk >> 6;
  const int c0   = (blk & 63) << 4;
  const int t    = s - l;
  if (t < 0 || t >= SS) return;

  const unsigned short* Wht = (l == 0) ? Wh0t : ((l == 1) ? Wh1t : Wh2t);
  const float* bias = (l == 0) ? bh0 : (bhx + (size_t)(l - 1) * 3 * SH);
  const int col = c0 + lrow;

  f32x4 acc0 = {0.f, 0.f, 0.f, 0.f};
  f32x4 acc1 = {0.f, 0.f, 0.f, 0.f};
  const unsigned short* rh = rh_bf + (size_t)l * SB * SH;
  gemm_k<SH>(rh + (size_t)(row0 + lrow) * SH + kg * 8,
             Wht + ((size_t)(2 * SH + col)) * SH + kg * 8, acc0, acc1);

  const float bsum = bias[2 * SH + col];
#pragma unroll
  for (int j = 0; j < 4; ++j) {
    const int row = row0 + kg * 4 + j;
    const size_t idx = ((size_t)l * SB + row) * SH + col;
    float v = acc0[j] + acc1[j] + gxg_f32[idx] + bsum;
    float e = __expf(2.f * v);
    float g = 1.f - 2.f / (e + 1.f);   // tanh(v), saturates safely
    float z = z_f32[idx];
    float hp = h_f32[idx];
    float hn = z * hp + (1.f - z) * g;
    h_f32[idx] = hn;
    h_bf[idx] = f2bf(hn);
  }
}

// ---------------- launcher ----------------
extern "C" void kernel_launch(void* const* d_in, const int* in_sizes, int n_in,
                              void* d_out, int out_size, void* d_ws, size_t ws_size,
                              hipStream_t stream) {
  (void)in_sizes; (void)n_in; (void)out_size; (void)ws_size;
  const float* x   = (const float*)d_in[0];
  const float* h0  = (const float*)d_in[1];
  const float* Wx0 = (const float*)d_in[2];
  const float* Wh0 = (const float*)d_in[3];
  const float* bh0 = (const float*)d_in[4];
  const float* Wx  = (const float*)d_in[5];
  const float* Wh  = (const float*)d_in[6];
  const float* bh  = (const float*)d_in[7];
  const float* Wy  = (const float*)d_in[8];
  const float* by  = (const float*)d_in[9];
  float* out = (float*)d_out;

  char* p = (char*)d_ws;
  auto take = [&](size_t bytes) {
    char* r = p;
    p += (bytes + 255) & ~(size_t)255;
    return r;
  };
  unsigned short* Wx0t = (unsigned short*)take((size_t)3 * SH * SI * 2);
  unsigned short* Wx1t = (unsigned short*)take((size_t)3 * SH * SH * 2);
  unsigned short* Wx2t = (unsigned short*)take((size_t)3 * SH * SH * 2);
  unsigned short* Wh0t = (unsigned short*)take((size_t)3 * SH * SH * 2);
  unsigned short* Wh1t = (unsigned short*)take((size_t)3 * SH * SH * 2);
  unsigned short* Wh2t = (unsigned short*)take((size_t)3 * SH * SH * 2);
  unsigned short* Wyt  = (unsigned short*)take((size_t)SO * SH * 2);
  unsigned short* h_bf = (unsigned short*)take((size_t)NL * SB * SH * 2);
  unsigned short* rh_bf = (unsigned short*)take((size_t)NL * SB * SH * 2);
  float* h_f32   = (float*)take((size_t)NL * SB * SH * 4);
  float* z_f32   = (float*)take((size_t)NL * SB * SH * 4);
  float* gxg_f32 = (float*)take((size_t)NL * SB * SH * 4);

  // weight transposition + bf16 conversion (N x K layout, B^T convention)
  k_transpose<<<dim3(3 * SH / 32, SI / 32), 256, 0, stream>>>(Wx0, Wx0t, SI, 3 * SH);
  k_transpose<<<dim3(3 * SH / 32, SH / 32), 256, 0, stream>>>(Wx, Wx1t, SH, 3 * SH);
  k_transpose<<<dim3(3 * SH / 32, SH / 32), 256, 0, stream>>>(Wx + (size_t)SH * 3 * SH, Wx2t, SH, 3 * SH);
  k_transpose<<<dim3(3 * SH / 32, SH / 32), 256, 0, stream>>>(Wh0, Wh0t, SH, 3 * SH);
  k_transpose<<<dim3(3 * SH / 32, SH / 32), 256, 0, stream>>>(Wh, Wh1t, SH, 3 * SH);
  k_transpose<<<dim3(3 * SH / 32, SH / 32), 256, 0, stream>>>(Wh + (size_t)SH * 3 * SH, Wh2t, SH, 3 * SH);
  k_transpose<<<dim3(SO / 32, SH / 32), 256, 0, stream>>>(Wy, Wyt, SH, SO);
  k_init_h<<<(NL * SB * SH) / 256, 256, 0, stream>>>(h0, h_f32, h_bf);

  // wavefront-pipelined stages: layer l handles t = s - l; y handles t = s - 3
  for (int s = 0; s <= SS + 2; ++s) {
    k_stageA<<<592, 256, 0, stream>>>(s, x, Wx0t, Wx1t, Wx2t, Wh0t, Wh1t, Wh2t, Wyt,
                                      bh0, bh, by, h_bf, h_f32, z_f32, rh_bf, gxg_f32, out);
    if (s <= SS + 1)
      k_stageB<<<192, 256, 0, stream>>>(s, Wh0t, Wh1t, Wh2t, bh0, bh,
                                        rh_bf, z_f32, gxg_f32, h_f32, h_bf);
  }
  k_final<<<(NL * SB * SH) / 256, 256, 0, stream>>>(h_f32, out);
}